// Round 9
// baseline (495.690 us; speedup 1.0000x reference)
//
#include <hip/hip_runtime.h>
#include <hip/hip_bf16.h>
#include <stdint.h>

#define B_   64
#define T_   2048
#define ENC_ 1024
#define DEC_ 1024
#define A_   512
#define M_   (B_ * T_)   // 131072

#define BM 128
#define BN 256
#define BK 64

typedef __bf16 bf16x8 __attribute__((ext_vector_type(8)));
typedef float  f32x4  __attribute__((ext_vector_type(4)));
typedef unsigned short u16;
typedef u16 u16x8 __attribute__((ext_vector_type(8)));

__device__ __forceinline__ float fast_tanh(float x) {
    float ax = fabsf(x);
    float e  = __expf(-2.0f * ax);     // in (0,1]
    float t  = (1.0f - e) / (1.0f + e);
    return copysignf(t, x);
}

// ---------------- U transpose + convert: Ut[n][k] = bf16(U[k][n]) ----------
__global__ __launch_bounds__(256) void k_transpose_U(
        const float* __restrict__ U, u16* __restrict__ Ut) {
    int idx = blockIdx.x * 256 + threadIdx.x;     // over 1024*512
    if (idx >= ENC_ * A_) return;
    int k = idx / A_, n = idx % A_;
    __bf16 v = (__bf16)U[idx];
    Ut[n * ENC_ + k] = *(u16*)&v;
}

// ---------------- f2[b][a] = sum_e s[b][e] * W[e][a]  (fp32) ---------------
__global__ __launch_bounds__(256) void k_f2(
        const float* __restrict__ s, const float* __restrict__ W,
        float* __restrict__ f2) {
    int b = blockIdx.x;
    int a0 = threadIdx.x;
    const float* srow = s + (size_t)b * DEC_;
    float acc0 = 0.f, acc1 = 0.f;
    for (int e = 0; e < DEC_; ++e) {
        float sv = srow[e];
        acc0 = fmaf(sv, W[(size_t)e * A_ + a0],       acc0);
        acc1 = fmaf(sv, W[(size_t)e * A_ + a0 + 256], acc1);
    }
    f2[(size_t)b * A_ + a0]       = acc0;
    f2[(size_t)b * A_ + a0 + 256] = acc1;
}

// ---------------- fused GEMM + tanh + dot(V): partial e --------------------
// 2048 blocks x 512 threads (8 waves, 2x4), wave tile 64x64 (acc = 64 AGPR).
// A: HBM -> regs -> bf16 -> LDS (DOUBLE-buffered 2x16KB, T2 swizzle), one
//    __syncthreads per K-tile, prefetch distance 1 (issue top, write bottom).
// B: read fragments DIRECTLY from Ut in L2 (1 MB, resident; 16B-aligned
//    loads, same logical layout the LDS held before). No gload_lds at all ->
//    nothing in flight at the barrier; drain is free.
// 2 blocks/CU (launch_bounds(512,4), LDS 32KB) -> cross-block overlap hides
// the staging/barrier gaps (R7 lesson).
__global__ __launch_bounds__(512, 4) void k_gemm_e(
        const float* __restrict__ h, const u16* __restrict__ Ut,
        const float* __restrict__ f2, const float* __restrict__ V,
        float* __restrict__ e_part) {
    __shared__ u16 Alds[2][BM * BK];   // 2 x 16 KB, swizzled

    const int tid  = threadIdx.x;
    const int lane = tid & 63;
    const int wid  = tid >> 6;         // 0..7
    const int wr   = wid >> 2;         // 0..1
    const int wc   = wid & 3;          // 0..3
    const int lr   = lane & 15;
    const int g    = lane >> 4;
    const int sw   = (lr & 7) << 3;    // read-side XOR (u16 units)

    // XCD-aware remap: column-pair adjacent on one XCD (A-panel L2 reuse).
    const int d    = blockIdx.x;
    const int xcd  = d & 7;
    const int s    = d >> 3;           // 0..255 per XCD
    const int m    = s & 1;
    const int pair = xcd * 128 + (s >> 1);   // 0..1023
    const int brow = pair * BM;
    const int bcol = m * BN;
    const int b    = brow / T_;        // uniform per block (T_ % BM == 0)

    // per-wave B base in Ut: n = bcol + wc*64 + nf*16 + lr
    const u16* bw = Ut + (size_t)(bcol + wc * 64 + lr) * ENC_ + g * 8;

    f32x4 acc[4][4] = {};              // 64 f32 -> AGPRs

    f32x4 ar[4];                       // in-flight A (fp32), 16 regs
    auto loadA = [&](int kt) {
        int flat0 = tid * 8;                       // logical u16 index
        int r = flat0 >> 6, c = flat0 & 63;
        const float* srcA = h + (size_t)(brow + r) * ENC_ + kt * BK + c;
        ar[0] = *(const f32x4*)srcA;
        ar[1] = *(const f32x4*)(srcA + 4);
        // second 512-thread chunk = rows r+64 (flat +4096 u16 -> +64 rows)
        const float* srcB = srcA + (size_t)64 * ENC_;
        ar[2] = *(const f32x4*)srcB;
        ar[3] = *(const f32x4*)(srcB + 4);
    };
    auto writeA = [&](int buf) {
#pragma unroll
        for (int it = 0; it < 2; ++it) {
            int flat = (it * 512 + tid) * 8;
            int r = flat >> 6;
            u16x8 w;
#pragma unroll
            for (int j = 0; j < 4; ++j) {
                __bf16 lo = (__bf16)ar[it * 2][j], hi = (__bf16)ar[it * 2 + 1][j];
                w[j]     = *(u16*)&lo;
                w[j + 4] = *(u16*)&hi;
            }
            *(u16x8*)&Alds[buf][flat ^ ((r & 7) << 3)] = w;
        }
    };

    // ---- prologue: tile 0 into buf 0 ----
    loadA(0);
    writeA(0);
    __syncthreads();

    for (int kt = 0; kt < ENC_ / BK; ++kt) {
        const int cur = kt & 1;
        if (kt + 1 < ENC_ / BK) loadA(kt + 1);     // issue early
        const int k0 = kt * BK;
#pragma unroll
        for (int kk = 0; kk < 2; ++kk) {
            bf16x8 af[4], bfr[4];
#pragma unroll
            for (int nf = 0; nf < 4; ++nf)         // B straight from L2
                bfr[nf] = *(const bf16x8*)(bw + (size_t)nf * 16 * ENC_
                                              + k0 + kk * 32);
#pragma unroll
            for (int mf = 0; mf < 4; ++mf)
                af[mf] = *(const bf16x8*)&Alds[cur][
                    (((wr * 64 + mf * 16 + lr) * 64) + kk * 32 + g * 8) ^ sw];
#pragma unroll
            for (int mf = 0; mf < 4; ++mf)
#pragma unroll
                for (int nf = 0; nf < 4; ++nf)
                    acc[mf][nf] = __builtin_amdgcn_mfma_f32_16x16x32_bf16(
                        af[mf], bfr[nf], acc[mf][nf], 0, 0, 0);
        }
        if (kt + 1 < ENC_ / BK) writeA(cur ^ 1);   // waits its own regs only
        __syncthreads();                           // nothing else in flight
    }

    // ---- epilogue: e_partial[m] = sum_n tanh(acc + f2) * V ----
    float vv[4], ff[4];
#pragma unroll
    for (int nf = 0; nf < 4; ++nf) {
        int n = bcol + wc * 64 + nf * 16 + lr;
        vv[nf] = V[n];
        ff[nf] = f2[(size_t)b * A_ + n];
    }
    const int p = m * 4 + wc;                     // 8 partial slices
    float* ep = e_part + (size_t)p * M_ + brow + wr * 64;
#pragma unroll
    for (int mf = 0; mf < 4; ++mf) {
        float sums[4];
#pragma unroll
        for (int i = 0; i < 4; ++i) {
            float sv = 0.f;
#pragma unroll
            for (int nf = 0; nf < 4; ++nf) {
                float x = acc[mf][nf][i] + ff[nf];
                sv = fmaf(fast_tanh(x), vv[nf], sv);
            }
#pragma unroll
            for (int mm = 1; mm < 16; mm <<= 1)
                sv += __shfl_xor(sv, mm, 64);     // reduce 16 cols
            sums[i] = sv;
        }
        if (lr == 0) {
#pragma unroll
            for (int i = 0; i < 4; ++i)
                ep[mf * 16 + g * 4 + i] = sums[i];
        }
    }
}

// ---------------- softmax over T per batch --------------------------------
__global__ __launch_bounds__(256) void k_softmax(
        const float* __restrict__ e_part, float* __restrict__ a_out) {
    const int b = blockIdx.x, tid = threadIdx.x;
    const int lane = tid & 63, w = tid >> 6;
    __shared__ float red[4], red2[4];

    float ls[8];
    float lmax = -1e30f;
#pragma unroll
    for (int i = 0; i < 8; ++i) {
        size_t mm = (size_t)b * T_ + i * 256 + tid;
        float sv = 0.f;
#pragma unroll
        for (int p = 0; p < 8; ++p) sv += e_part[(size_t)p * M_ + mm];
        ls[i] = sv;
        lmax = fmaxf(lmax, sv);
    }
#pragma unroll
    for (int mm = 1; mm < 64; mm <<= 1) lmax = fmaxf(lmax, __shfl_xor(lmax, mm, 64));
    if (lane == 0) red[w] = lmax;
    __syncthreads();
    float bmax = fmaxf(fmaxf(red[0], red[1]), fmaxf(red[2], red[3]));

    float lsum = 0.f;
#pragma unroll
    for (int i = 0; i < 8; ++i) { ls[i] = __expf(ls[i] - bmax); lsum += ls[i]; }
#pragma unroll
    for (int mm = 1; mm < 64; mm <<= 1) lsum += __shfl_xor(lsum, mm, 64);
    if (lane == 0) red2[w] = lsum;
    __syncthreads();
    float inv = 1.0f / (red2[0] + red2[1] + red2[2] + red2[3]);

#pragma unroll
    for (int i = 0; i < 8; ++i)
        a_out[(size_t)b * T_ + i * 256 + tid] = ls[i] * inv;
}

// ---------------- context partials: c_part[tc][b][e], tc-chunk = 128 ------
__global__ __launch_bounds__(256) void k_ctx_part(
        const float* __restrict__ h, const float* __restrict__ a,
        float* __restrict__ c_part) {
    const int b = blockIdx.x, tc = blockIdx.y, tid = threadIdx.x;
    __shared__ float alds[128];
    if (tid < 128)
        alds[tid] = a[(size_t)b * T_ + tc * 128 + tid];
    __syncthreads();

    float4 acc = {0.f, 0.f, 0.f, 0.f};
    const float* hb = h + ((size_t)b * T_ + (size_t)tc * 128) * ENC_ + tid * 4;
    for (int t = 0; t < 128; ++t) {
        float av = alds[t];
        float4 hv = *(const float4*)(hb + (size_t)t * ENC_);
        acc.x = fmaf(av, hv.x, acc.x);
        acc.y = fmaf(av, hv.y, acc.y);
        acc.z = fmaf(av, hv.z, acc.z);
        acc.w = fmaf(av, hv.w, acc.w);
    }
    *(float4*)&c_part[((size_t)(tc * 64 + b)) * ENC_ + tid * 4] = acc;
}

// ---------------- final context reduce ------------------------------------
__global__ __launch_bounds__(256) void k_ctx_final(
        const float* __restrict__ c_part, float* __restrict__ c_out) {
    int idx = blockIdx.x * 256 + threadIdx.x;   // 16384 threads
    int off = idx * 4;
    float4 sv = {0.f, 0.f, 0.f, 0.f};
#pragma unroll
    for (int tc = 0; tc < 16; ++tc) {
        float4 v = *(const float4*)&c_part[(size_t)tc * 64 * 1024 + off];
        sv.x += v.x; sv.y += v.y; sv.z += v.z; sv.w += v.w;
    }
    *(float4*)&c_out[off] = sv;
}

extern "C" void kernel_launch(void* const* d_in, const int* in_sizes, int n_in,
                              void* d_out, int out_size, void* d_ws, size_t ws_size,
                              hipStream_t stream) {
    const float* h = (const float*)d_in[0];
    const float* s = (const float*)d_in[1];
    const float* U = (const float*)d_in[2];
    const float* W = (const float*)d_in[3];
    const float* V = (const float*)d_in[4];

    float* out   = (float*)d_out;
    float* c_out = out;                         // [64][1][1024] -> 65536 floats
    float* a_out = out + 64 * 1024;             // [64][2048][1] -> 131072 floats

    char* ws = (char*)d_ws;
    u16*   Ut     = (u16*)ws;                                       // 1 MB
    float* f2     = (float*)(ws + (1 << 20));                       // 128 KB
    float* e_part = (float*)(ws + (1 << 20) + (128 << 10));         // 4 MB
    float* c_part = e_part;   // overlay: e_part dead after k_softmax

    k_transpose_U<<<2048, 256, 0, stream>>>(U, Ut);
    k_f2<<<64, 256, 0, stream>>>(s, W, f2);

    k_gemm_e<<<2048, 512, 0, stream>>>(h, Ut, f2, V, e_part);

    k_softmax<<<64, 256, 0, stream>>>(e_part, a_out);

    dim3 gc(64, 16);
    k_ctx_part<<<gc, 256, 0, stream>>>(h, a_out, c_part);
    k_ctx_final<<<64, 256, 0, stream>>>(c_part, c_out);
}

// Round 10
// 360.890 us; speedup vs baseline: 1.3735x; 1.3735x over previous
//
#include <hip/hip_runtime.h>
#include <hip/hip_bf16.h>
#include <stdint.h>

#define B_   64
#define T_   2048
#define ENC_ 1024
#define DEC_ 1024
#define A_   512
#define M_   (B_ * T_)   // 131072

#define BM 128
#define BN 256
#define BK 64

typedef __bf16 bf16x8 __attribute__((ext_vector_type(8)));
typedef float  f32x4  __attribute__((ext_vector_type(4)));
typedef unsigned short u16;

__device__ __forceinline__ float fast_tanh(float x) {
    float ax = fabsf(x);
    float e  = __expf(-2.0f * ax);     // in (0,1]
    float t  = (1.0f - e) / (1.0f + e);
    return copysignf(t, x);
}

// ---------------- U transpose + convert: Ut[n][k] = bf16(U[k][n]) ----------
__global__ __launch_bounds__(256) void k_transpose_U(
        const float* __restrict__ U, u16* __restrict__ Ut) {
    int idx = blockIdx.x * 256 + threadIdx.x;     // over 1024*512
    if (idx >= ENC_ * A_) return;
    int k = idx / A_, n = idx % A_;
    __bf16 v = (__bf16)U[idx];
    Ut[n * ENC_ + k] = *(u16*)&v;
}

// ---------------- f2[b][a] = sum_e s[b][e] * W[e][a]  (fp32) ---------------
__global__ __launch_bounds__(256) void k_f2(
        const float* __restrict__ s, const float* __restrict__ W,
        float* __restrict__ f2) {
    int b = blockIdx.x;
    int a0 = threadIdx.x;
    const float* srow = s + (size_t)b * DEC_;
    float acc0 = 0.f, acc1 = 0.f;
    for (int e = 0; e < DEC_; ++e) {
        float sv = srow[e];
        acc0 = fmaf(sv, W[(size_t)e * A_ + a0],       acc0);
        acc1 = fmaf(sv, W[(size_t)e * A_ + a0 + 256], acc1);
    }
    f2[(size_t)b * A_ + a0]       = acc0;
    f2[(size_t)b * A_ + a0 + 256] = acc1;
}

// ---------------- fused GEMM + tanh + dot(V): partial e --------------------
// 2048 blocks x 512 threads (8 waves, 2x4), wave tile 64x64 (acc = 64 AGPR).
// BOTH operands staged via global_load_lds with pre-swizzled SOURCE (rule 21):
//   A: raw fp32 [128][64] tile (32 KB), granule (16B) swizzle s^=(row&7);
//      fp32->bf16 conversion happens on the consume side (VALU overlaps the
//      co-resident block's MFMA, m114). Zero reg/VALU/ds_write in staging.
//   B: bf16 [256][64] (32 KB), u16-chunk swizzle (proven R2-R7).
// Single-buffered, 2 barriers per K-tile; 64 KB LDS -> 2 blocks/CU
// (launch_bounds(512,4)); cross-block overlap hides stage bursts (R7 lesson).
__global__ __launch_bounds__(512, 4) void k_gemm_e(
        const float* __restrict__ h, const u16* __restrict__ Ut,
        const float* __restrict__ f2, const float* __restrict__ V,
        float* __restrict__ e_part) {
    __shared__ float Af[BM * BK];      // 32 KB fp32, granule-swizzled
    __shared__ u16   Blds[BN * BK];    // 32 KB bf16, swizzled

    const int tid  = threadIdx.x;
    const int lane = tid & 63;
    const int wid  = tid >> 6;         // 0..7
    const int wr   = wid >> 2;         // 0..1
    const int wc   = wid & 3;          // 0..3
    const int lr   = lane & 15;
    const int g    = lane >> 4;
    const int swb  = (lr & 7) << 3;    // B read-side XOR (u16 units)
    const int swa  = lr & 7;           // A read-side granule XOR

    // XCD-aware remap: column-pair adjacent on one XCD (A-panel L2/L3 reuse).
    const int d    = blockIdx.x;
    const int xcd  = d & 7;
    const int s    = d >> 3;           // 0..255 per XCD
    const int m    = s & 1;
    const int pair = xcd * 128 + (s >> 1);   // 0..1023
    const int brow = pair * BM;
    const int bcol = m * BN;
    const int b    = brow / T_;        // uniform per block (T_ % BM == 0)

    f32x4 acc[4][4] = {};              // 64 f32 -> AGPRs

    for (int kt = 0; kt < ENC_ / BK; ++kt) {
        const int k0 = kt * BK;

        // ---- stage A: fp32 global_load_lds, LINEAR dest, swizzled SOURCE --
        // granule G (16B = 4 floats): row = G>>4, slot = G&15; dest slot
        // holds logical col-chunk slot^(row&7).
#pragma unroll
        for (int it = 0; it < 4; ++it) {
            int G   = it * 512 + tid;
            int row = G >> 4, sl = G & 15;
            const float* src = h + (size_t)(brow + row) * ENC_ + k0
                                 + ((sl ^ (row & 7)) << 2);
            float* dst = Af + (size_t)(it * 512 + wid * 64) * 4; // wave-uniform
            __builtin_amdgcn_global_load_lds(
                (const __attribute__((address_space(1))) void*)src,
                (__attribute__((address_space(3))) void*)dst, 16, 0, 0);
        }
        // ---- stage B: bf16 global_load_lds, LINEAR dest, swizzled SOURCE --
#pragma unroll
        for (int it = 0; it < 4; ++it) {
            int G  = it * 512 + tid;                  // 16B granule index
            int n  = G >> 3;
            int kc = ((G & 7) ^ (n & 7)) << 3;        // swizzled k-offset
            const u16* src = Ut + (size_t)(bcol + n) * ENC_ + k0 + kc;
            u16* dst = &Blds[(size_t)(it * 512 + wid * 64) * 8];
            __builtin_amdgcn_global_load_lds(
                (const __attribute__((address_space(1))) void*)src,
                (__attribute__((address_space(3))) void*)dst, 16, 0, 0);
        }
        __syncthreads();   // drains the 8 gload_lds (vmcnt only)

#pragma unroll
        for (int kk = 0; kk < 2; ++kk) {
            bf16x8 af[4], bfr[4];
#pragma unroll
            for (int mf = 0; mf < 4; ++mf) {
                int row  = wr * 64 + mf * 16 + lr;    // row&7 == lr&7
                int base = row * 64 + kk * 32;
                f32x4 f0 = *(const f32x4*)&Af[base + (((2 * g)     ^ swa) << 2)];
                f32x4 f1 = *(const f32x4*)&Af[base + (((2 * g + 1) ^ swa) << 2)];
#pragma unroll
                for (int j = 0; j < 4; ++j) {
                    af[mf][j]     = (__bf16)f0[j];
                    af[mf][j + 4] = (__bf16)f1[j];
                }
            }
#pragma unroll
            for (int nf = 0; nf < 4; ++nf)
                bfr[nf] = *(const bf16x8*)&Blds[
                    (((wc * 64 + nf * 16 + lr) * 64) + kk * 32 + g * 8) ^ swb];
#pragma unroll
            for (int mf = 0; mf < 4; ++mf)
#pragma unroll
                for (int nf = 0; nf < 4; ++nf)
                    acc[mf][nf] = __builtin_amdgcn_mfma_f32_16x16x32_bf16(
                        af[mf], bfr[nf], acc[mf][nf], 0, 0, 0);
        }
        __syncthreads();   // protect LDS before next-tile staging
    }

    // ---- epilogue: e_partial[m] = sum_n tanh(acc + f2) * V ----
    float vv[4], ff[4];
#pragma unroll
    for (int nf = 0; nf < 4; ++nf) {
        int n = bcol + wc * 64 + nf * 16 + lr;
        vv[nf] = V[n];
        ff[nf] = f2[(size_t)b * A_ + n];
    }
    const int p = m * 4 + wc;                     // 8 partial slices
    float* ep = e_part + (size_t)p * M_ + brow + wr * 64;
#pragma unroll
    for (int mf = 0; mf < 4; ++mf) {
        float sums[4];
#pragma unroll
        for (int i = 0; i < 4; ++i) {
            float sv = 0.f;
#pragma unroll
            for (int nf = 0; nf < 4; ++nf) {
                float x = acc[mf][nf][i] + ff[nf];
                sv = fmaf(fast_tanh(x), vv[nf], sv);
            }
#pragma unroll
            for (int mm = 1; mm < 16; mm <<= 1)
                sv += __shfl_xor(sv, mm, 64);     // reduce 16 cols
            sums[i] = sv;
        }
        if (lr == 0) {
#pragma unroll
            for (int i = 0; i < 4; ++i)
                ep[mf * 16 + g * 4 + i] = sums[i];
        }
    }
}

// ---------------- softmax over T per batch --------------------------------
__global__ __launch_bounds__(256) void k_softmax(
        const float* __restrict__ e_part, float* __restrict__ a_out) {
    const int b = blockIdx.x, tid = threadIdx.x;
    const int lane = tid & 63, w = tid >> 6;
    __shared__ float red[4], red2[4];

    float ls[8];
    float lmax = -1e30f;
#pragma unroll
    for (int i = 0; i < 8; ++i) {
        size_t mm = (size_t)b * T_ + i * 256 + tid;
        float sv = 0.f;
#pragma unroll
        for (int p = 0; p < 8; ++p) sv += e_part[(size_t)p * M_ + mm];
        ls[i] = sv;
        lmax = fmaxf(lmax, sv);
    }
#pragma unroll
    for (int mm = 1; mm < 64; mm <<= 1) lmax = fmaxf(lmax, __shfl_xor(lmax, mm, 64));
    if (lane == 0) red[w] = lmax;
    __syncthreads();
    float bmax = fmaxf(fmaxf(red[0], red[1]), fmaxf(red[2], red[3]));

    float lsum = 0.f;
#pragma unroll
    for (int i = 0; i < 8; ++i) { ls[i] = __expf(ls[i] - bmax); lsum += ls[i]; }
#pragma unroll
    for (int mm = 1; mm < 64; mm <<= 1) lsum += __shfl_xor(lsum, mm, 64);
    if (lane == 0) red2[w] = lsum;
    __syncthreads();
    float inv = 1.0f / (red2[0] + red2[1] + red2[2] + red2[3]);

#pragma unroll
    for (int i = 0; i < 8; ++i)
        a_out[(size_t)b * T_ + i * 256 + tid] = ls[i] * inv;
}

// ---------------- context partials: c_part[tc][b][e], tc-chunk = 128 ------
__global__ __launch_bounds__(256) void k_ctx_part(
        const float* __restrict__ h, const float* __restrict__ a,
        float* __restrict__ c_part) {
    const int b = blockIdx.x, tc = blockIdx.y, tid = threadIdx.x;
    __shared__ float alds[128];
    if (tid < 128)
        alds[tid] = a[(size_t)b * T_ + tc * 128 + tid];
    __syncthreads();

    float4 acc = {0.f, 0.f, 0.f, 0.f};
    const float* hb = h + ((size_t)b * T_ + (size_t)tc * 128) * ENC_ + tid * 4;
    for (int t = 0; t < 128; ++t) {
        float av = alds[t];
        float4 hv = *(const float4*)(hb + (size_t)t * ENC_);
        acc.x = fmaf(av, hv.x, acc.x);
        acc.y = fmaf(av, hv.y, acc.y);
        acc.z = fmaf(av, hv.z, acc.z);
        acc.w = fmaf(av, hv.w, acc.w);
    }
    *(float4*)&c_part[((size_t)(tc * 64 + b)) * ENC_ + tid * 4] = acc;
}

// ---------------- final context reduce ------------------------------------
__global__ __launch_bounds__(256) void k_ctx_final(
        const float* __restrict__ c_part, float* __restrict__ c_out) {
    int idx = blockIdx.x * 256 + threadIdx.x;   // 16384 threads
    int off = idx * 4;
    float4 sv = {0.f, 0.f, 0.f, 0.f};
#pragma unroll
    for (int tc = 0; tc < 16; ++tc) {
        float4 v = *(const float4*)&c_part[(size_t)tc * 64 * 1024 + off];
        sv.x += v.x; sv.y += v.y; sv.z += v.z; sv.w += v.w;
    }
    *(float4*)&c_out[off] = sv;
}

extern "C" void kernel_launch(void* const* d_in, const int* in_sizes, int n_in,
                              void* d_out, int out_size, void* d_ws, size_t ws_size,
                              hipStream_t stream) {
    const float* h = (const float*)d_in[0];
    const float* s = (const float*)d_in[1];
    const float* U = (const float*)d_in[2];
    const float* W = (const float*)d_in[3];
    const float* V = (const float*)d_in[4];

    float* out   = (float*)d_out;
    float* c_out = out;                         // [64][1][1024] -> 65536 floats
    float* a_out = out + 64 * 1024;             // [64][2048][1] -> 131072 floats

    char* ws = (char*)d_ws;
    u16*   Ut     = (u16*)ws;                                       // 1 MB
    float* f2     = (float*)(ws + (1 << 20));                       // 128 KB
    float* e_part = (float*)(ws + (1 << 20) + (128 << 10));         // 4 MB
    float* c_part = e_part;   // overlay: e_part dead after k_softmax

    k_transpose_U<<<2048, 256, 0, stream>>>(U, Ut);
    k_f2<<<64, 256, 0, stream>>>(s, W, f2);

    k_gemm_e<<<2048, 512, 0, stream>>>(h, Ut, f2, V, e_part);

    k_softmax<<<64, 256, 0, stream>>>(e_part, a_out);

    dim3 gc(64, 16);
    k_ctx_part<<<gc, 256, 0, stream>>>(h, a_out, c_part);
    k_ctx_final<<<64, 256, 0, stream>>>(c_part, c_out);
}